// Round 10
// baseline (485.384 us; speedup 1.0000x reference)
//
#include <hip/hip_runtime.h>
#include <hip/hip_fp16.h>
#include <math.h>

#define NEG_SLOPE 0.2f
#define NUM_GRAPHS 256

typedef float v2f __attribute__((ext_vector_type(2)));

// ---- 16-lane (quarter-wave) float sum; result broadcast within each 16-group ----
__device__ __forceinline__ float hsum16_bcast(float x) {
    x += __int_as_float(__builtin_amdgcn_update_dpp(0, __float_as_int(x), 0x111, 0xF, 0xF, false)); // row_shr:1
    x += __int_as_float(__builtin_amdgcn_update_dpp(0, __float_as_int(x), 0x112, 0xF, 0xF, false)); // row_shr:2
    x += __int_as_float(__builtin_amdgcn_update_dpp(0, __float_as_int(x), 0x114, 0xF, 0xF, false)); // row_shr:4
    x += __int_as_float(__builtin_amdgcn_update_dpp(0, __float_as_int(x), 0x118, 0xF, 0xF, false)); // row_shr:8
    return __int_as_float(__builtin_amdgcn_ds_swizzle(__float_as_int(x), 0x1F0));
}

// packed-fp32 edge score partial: att . leaky_relu(v + xr), 4 features/lane
__device__ __forceinline__ float edge_score(v2f vlo, v2f vhi, v2f xlo, v2f xhi, v2f alo, v2f ahi) {
    v2f t0 = vlo + xlo;
    v2f t1 = vhi + xhi;
    t0 = __builtin_elementwise_max(t0, NEG_SLOPE * t0);
    t1 = __builtin_elementwise_max(t1, NEG_SLOPE * t1);
    v2f p = __builtin_elementwise_fma(alo, t0, ahi * t1);
    return p.x + p.y;
}

__device__ __forceinline__ void store16_f16(__half* Y16, int orow, int cbase, const float* acc) {
    __half2 h8[8];
#pragma unroll
    for (int c = 0; c < 8; ++c) h8[c] = __floats2half2_rn(acc[2*c], acc[2*c+1]);
    uint4* d16 = (uint4*)(Y16 + (size_t)orow * 64 + cbase);
    d16[0] = ((uint4*)h8)[0];
    d16[1] = ((uint4*)h8)[1];
}

__device__ __forceinline__ void store16_f32(float* Y32, int orow, int cbase, const float* acc) {
    float4* d32 = (float4*)(Y32 + (size_t)orow * 64 + cbase);
#pragma unroll
    for (int i = 0; i < 4; ++i) d32[i] = ((const float4*)acc)[i];
}

// ---------------- K1: heterogeneous mega-kernel ----------------
// blocks [0, gemmBlocks)            : layer-1 dual GEMM (VALU-bound)
// blocks [gemmBlocks, +buildBlocks) : edge scatter build (atomic-latency-bound) + gbound

__global__ void k_build_gemm(const int* __restrict__ src, const int* __restrict__ dst,
                             int* __restrict__ cnt, int* __restrict__ csrF,
                             const int* __restrict__ batch, int* __restrict__ gstart,
                             const float* __restrict__ X,
                             const float* __restrict__ Wl, const float* __restrict__ Wr,
                             __half* __restrict__ Yl16, float* __restrict__ Yr32,
                             int E, int N, int gemmBlocks) {
    __shared__ float sXT[64][65];
    if ((int)blockIdx.x < gemmBlocks) {
        int t = threadIdx.x;
        int r0 = blockIdx.x * 64;
        {
            int lr = t >> 2;
            int c0s = (t & 3) * 16;
            int row = r0 + lr;
            float4 tmp[4];
            if (row < N) {
                const float4* Xv = (const float4*)(X + (size_t)row * 64 + c0s);
#pragma unroll
                for (int i = 0; i < 4; ++i) tmp[i] = Xv[i];
            } else {
#pragma unroll
                for (int i = 0; i < 4; ++i) tmp[i] = make_float4(0.f, 0.f, 0.f, 0.f);
            }
#pragma unroll
            for (int i = 0; i < 4; ++i) {
                sXT[c0s + i*4 + 0][lr] = tmp[i].x;
                sXT[c0s + i*4 + 1][lr] = tmp[i].y;
                sXT[c0s + i*4 + 2][lr] = tmp[i].z;
                sXT[c0s + i*4 + 3][lr] = tmp[i].w;
            }
        }
        __syncthreads();
        int lane = t & 63;
        int cbase = __builtin_amdgcn_readfirstlane((t >> 6) * 16);
        int orow = r0 + lane;
        float accl[16], accr[16];
#pragma unroll
        for (int c = 0; c < 16; ++c) { accl[c] = 0.f; accr[c] = 0.f; }
        for (int k = 0; k < 64; ++k) {
            float xk = sXT[k][lane];
            const float* wl = Wl + k * 64 + cbase;
            const float* wr = Wr + k * 64 + cbase;
#pragma unroll
            for (int c = 0; c < 16; ++c) { accl[c] += xk * wl[c]; accr[c] += xk * wr[c]; }
        }
        if (orow < N) {
            store16_f16(Yl16, orow, cbase, accl);
            store16_f32(Yr32, orow, cbase, accr);
        }
    } else {
        int idx = ((int)blockIdx.x - gemmBlocks) * blockDim.x + threadIdx.x;
        if (idx < E) {
            int d = dst[idx];
            int slot = atomicAdd(&cnt[d], 1);
            if (slot < 64) csrF[((size_t)d << 6) + slot] = src[idx];
        } else if (idx < E + N) {
            int i = idx - E;
            int b = batch[i];
            if (i == 0) {
                for (int g = 0; g <= b; ++g) gstart[g] = 0;
            } else {
                int pb = batch[i - 1];
                for (int g = pb + 1; g <= b; ++g) gstart[g] = i;
            }
            if (i == N - 1) {
                for (int g = b + 1; g <= NUM_GRAPHS; ++g) gstart[g] = N;
            }
        }
    }
}

// ---------------- agg machinery (shared) ----------------

#define AGG_UNPACK(u, vlo, vhi)                                                 \
    float2 vlo##_c = __half22float2(*(__half2*)&(u).x);                         \
    float2 vhi##_c = __half22float2(*(__half2*)&(u).y);                         \
    v2f vlo = {vlo##_c.x, vlo##_c.y};                                           \
    v2f vhi = {vhi##_c.x, vhi##_c.y};

#define AGG_CONSUME(uA, uB)                                                     \
    {                                                                           \
        AGG_UNPACK(uA, vAlo, vAhi);                                             \
        AGG_UNPACK(uB, vBlo, vBhi);                                             \
        float pA = hsum16_bcast(edge_score(vAlo, vAhi, xlo, xhi, alo, ahi));    \
        float pB = hsum16_bcast(edge_score(vBlo, vBhi, xlo, xhi, alo, ahi));    \
        float wA = __expf(pA), wB = __expf(pB);                                 \
        l += wA + wB;                                                           \
        acclo = __builtin_elementwise_fma(vAlo, (v2f){wA, wA}, acclo);          \
        acchi = __builtin_elementwise_fma(vAhi, (v2f){wA, wA}, acchi);          \
        acclo = __builtin_elementwise_fma(vBlo, (v2f){wB, wB}, acclo);          \
        acchi = __builtin_elementwise_fma(vBhi, (v2f){wB, wB}, acchi);          \
    }

// full agg body (software-pipelined, 4 edges/wave quarter-wave scheme) ending
// with l/acclo/acchi fully reduced across slots on ALL lanes.
#define AGG_BODY(xl, xr)                                                        \
    int lane = threadIdx.x & 63;                                                \
    int q = lane & 15, slot = lane >> 4;                                        \
    int deg = cnt[wid];                                                         \
    deg = (deg < 64) ? deg : 64;                                                \
    const int* crow = csrF + ((size_t)wid << 6);                                \
    int n8 = deg & ~7;                                                          \
    uint2 uA, uB;                                                               \
    if (n8 >= 8) {                                                              \
        int sA = crow[slot];                                                    \
        int sB = crow[4 + slot];                                                \
        uA = *(const uint2*)((xl) + ((size_t)sA << 6) + 4 * q);                 \
        uB = *(const uint2*)((xl) + ((size_t)sB << 6) + 4 * q);                 \
    }                                                                           \
    float4 xr4 = *(const float4*)((xr) + (size_t)wid * 64 + 4 * q);             \
    float4 at4 = *(const float4*)(att + 4 * q);                                 \
    v2f xlo = {xr4.x, xr4.y}, xhi = {xr4.z, xr4.w};                             \
    v2f alo = {at4.x, at4.y}, ahi = {at4.z, at4.w};                             \
    uint2 us = *(const uint2*)((xl) + ((size_t)wid << 6) + 4 * q);              \
    AGG_UNPACK(us, vslo, vshi);                                                 \
    float ps = hsum16_bcast(edge_score(vslo, vshi, xlo, xhi, alo, ahi));        \
    float wsf = (slot == 0) ? __expf(ps) : 0.f;                                 \
    float l = wsf;                                                              \
    v2f acclo = vslo * (v2f){wsf, wsf};                                         \
    v2f acchi = vshi * (v2f){wsf, wsf};                                         \
    if (n8 >= 8) {                                                              \
        for (int j = 8; j < n8; j += 8) {                                       \
            int sA2 = crow[j + slot];                                           \
            int sB2 = crow[j + 4 + slot];                                       \
            uint2 uA2 = *(const uint2*)((xl) + ((size_t)sA2 << 6) + 4 * q);     \
            uint2 uB2 = *(const uint2*)((xl) + ((size_t)sB2 << 6) + 4 * q);     \
            AGG_CONSUME(uA, uB);                                                \
            uA = uA2; uB = uB2;                                                 \
        }                                                                       \
        AGG_CONSUME(uA, uB);                                                    \
    }                                                                           \
    int jt = n8;                                                                \
    if (jt < deg) {                                                             \
        int jA = jt + slot, jB = jt + 4 + slot;                                 \
        bool vA = jA < deg, vB = jB < deg;                                      \
        int sA = vA ? crow[jA] : wid;                                           \
        int sB = vB ? crow[jB] : wid;                                           \
        uint2 tA = *(const uint2*)((xl) + ((size_t)sA << 6) + 4 * q);           \
        uint2 tB = *(const uint2*)((xl) + ((size_t)sB << 6) + 4 * q);           \
        AGG_UNPACK(tA, vAlo, vAhi);                                             \
        AGG_UNPACK(tB, vBlo, vBhi);                                             \
        float pA = hsum16_bcast(edge_score(vAlo, vAhi, xlo, xhi, alo, ahi));    \
        float pB = hsum16_bcast(edge_score(vBlo, vBhi, xlo, xhi, alo, ahi));    \
        float wA = vA ? __expf(pA) : 0.f;                                       \
        float wB = vB ? __expf(pB) : 0.f;                                       \
        l += wA + wB;                                                           \
        acclo = __builtin_elementwise_fma(vAlo, (v2f){wA, wA}, acclo);          \
        acchi = __builtin_elementwise_fma(vAhi, (v2f){wA, wA}, acchi);          \
        acclo = __builtin_elementwise_fma(vBlo, (v2f){wB, wB}, acclo);          \
        acchi = __builtin_elementwise_fma(vBhi, (v2f){wB, wB}, acchi);          \
    }                                                                           \
    _Pragma("unroll")                                                           \
    for (int o = 16; o <= 32; o <<= 1) {                                        \
        l += __shfl_xor(l, o, 64);                                              \
        acclo.x += __shfl_xor(acclo.x, o, 64);                                  \
        acclo.y += __shfl_xor(acclo.y, o, 64);                                  \
        acchi.x += __shfl_xor(acchi.x, o, 64);                                  \
        acchi.y += __shfl_xor(acchi.y, o, 64);                                  \
    }

// ---------------- fused agg + relu + row@W (layers 1,2) ----------------
// After the agg reduce, every lane holds the full sums; apply softmax-normalize,
// bias, relu -> node row h (distributed 4 feats/lane, replicated across slots).
// Then y = h @ W via 16x4 shuffle-broadcast matvec; write y as fp16 (next xl)
// and fp32 (next xr, IN PLACE over this layer's xr: row wid is only ever
// touched by wave wid, so the single fp32 feature buffer is updated in place).

__global__ void k_agg_gemm(const __half* __restrict__ xl, const float* xr,
                           const float* __restrict__ att, const float* __restrict__ bias,
                           const int* __restrict__ cnt, const int* __restrict__ csrF,
                           const float* __restrict__ W,
                           __half* __restrict__ y16, float* y32, int N) {
    int wid = (blockIdx.x * blockDim.x + threadIdx.x) >> 6;
    if (wid >= N) return;
    AGG_BODY(xl, xr);

    float rl = 1.0f / l;
    float4 bv = *(const float4*)(bias + 4 * q);
    float rr0 = fmaxf(acclo.x * rl + bv.x, 0.f);
    float rr1 = fmaxf(acclo.y * rl + bv.y, 0.f);
    float rr2 = fmaxf(acchi.x * rl + bv.z, 0.f);
    float rr3 = fmaxf(acchi.y * rl + bv.w, 0.f);

    // y[lane] = sum_f h[f] * W[f*64 + lane]; feature 4*kq+r lives in rr_r of lane kq
    float ya = 0.f, yb = 0.f, yc = 0.f, yd = 0.f;
#pragma unroll
    for (int kq = 0; kq < 16; ++kq) {
        float b0 = __shfl(rr0, kq, 64);
        float b1 = __shfl(rr1, kq, 64);
        float b2 = __shfl(rr2, kq, 64);
        float b3 = __shfl(rr3, kq, 64);
        const float* wrow = W + kq * 256 + lane;
        ya = fmaf(b0, wrow[0],   ya);
        yb = fmaf(b1, wrow[64],  yb);
        yc = fmaf(b2, wrow[128], yc);
        yd = fmaf(b3, wrow[192], yd);
    }
    float y = (ya + yb) + (yc + yd);
    y16[(size_t)wid * 64 + lane] = __float2half(y);
    y32[(size_t)wid * 64 + lane] = y;
}

// ---------------- plain agg (layer 3, no relu, no gemm); out may equal xr ----

__global__ void k_agg16(const __half* __restrict__ xl, const float* xr,
                        const float* __restrict__ att, const float* __restrict__ bias,
                        const int* __restrict__ cnt, const int* __restrict__ csrF,
                        float* out, int N) {
    int wid = (blockIdx.x * blockDim.x + threadIdx.x) >> 6;
    if (wid >= N) return;
    AGG_BODY(xl, xr);

    if (slot == 0) {
        float rl = 1.0f / l;
        float4 bv = *(const float4*)(bias + 4 * q);
        float o0 = acclo.x * rl + bv.x;
        float o1 = acclo.y * rl + bv.y;
        float o2 = acchi.x * rl + bv.z;
        float o3 = acchi.y * rl + bv.w;
        *(float4*)(out + (size_t)wid * 64 + 4 * q) = make_float4(o0, o1, o2, o3);
    }
}

// ---------------- fused mean pool + final linear ----------------

__global__ void k_pool_final(const float* __restrict__ h, const int* __restrict__ gstart,
                             const float* __restrict__ Wlin, const float* __restrict__ blin,
                             float* __restrict__ out) {
    int wave = (blockIdx.x * blockDim.x + threadIdx.x) >> 6;
    int lane = threadIdx.x & 63;
    if (wave >= NUM_GRAPHS) return;
    int g = wave;
    int i0 = gstart[g], i1 = gstart[g + 1];
    float s0 = 0.f, s1 = 0.f, s2 = 0.f, s3 = 0.f;
    int i = i0;
    for (; i + 4 <= i1; i += 4) {
        s0 += h[(size_t)i * 64 + lane];
        s1 += h[(size_t)(i + 1) * 64 + lane];
        s2 += h[(size_t)(i + 2) * 64 + lane];
        s3 += h[(size_t)(i + 3) * 64 + lane];
    }
    for (; i < i1; ++i) s0 += h[(size_t)i * 64 + lane];
    float s = (s0 + s1) + (s2 + s3);
    float c = (float)((i1 - i0) > 1 ? (i1 - i0) : 1);
    float pld = s / c;
    float acc = blin[lane];
    for (int k = 0; k < 64; ++k) {
        acc += __shfl(pld, k, 64) * Wlin[k * 64 + lane];
    }
    out[g * 64 + lane] = acc;
}

// ---------------- launch ----------------

extern "C" void kernel_launch(void* const* d_in, const int* in_sizes, int n_in,
                              void* d_out, int out_size, void* d_ws, size_t ws_size,
                              hipStream_t stream) {
    const float* x    = (const float*)d_in[0];
    const int*   ei   = (const int*)d_in[1];
    const int*   batch= (const int*)d_in[2];
    const float* W1l  = (const float*)d_in[3];
    const float* W1r  = (const float*)d_in[4];
    const float* att1 = (const float*)d_in[5];
    const float* b1   = (const float*)d_in[6];
    const float* W2   = (const float*)d_in[7];
    const float* att2 = (const float*)d_in[8];
    const float* b2   = (const float*)d_in[9];
    const float* W3   = (const float*)d_in[10];
    const float* att3 = (const float*)d_in[11];
    const float* b3   = (const float*)d_in[12];
    const float* Wlin = (const float*)d_in[13];
    const float* blin = (const float*)d_in[14];

    const int N = in_sizes[0] / 64;
    const int E = in_sizes[1] / 2;
    const int* src = ei;
    const int* dst = ei + E;

    char* p = (char*)d_ws;
    auto alloc = [&](size_t bytes) -> void* {
        void* r = (void*)p;
        p += (bytes + 255) & ~(size_t)255;
        return r;
    };
    float*  F    = (float*)alloc((size_t)N * 64 * 4);    // fp32 feature buffer (in-place xr/h)
    __half* H1   = (__half*)alloc((size_t)N * 64 * 2);   // fp16 gather payload (ping)
    __half* H2   = (__half*)alloc((size_t)N * 64 * 2);   // fp16 gather payload (pong)
    int*    csrF = (int*)alloc((size_t)N * 64 * 4);      // fixed-stride CSR, 64 slots/node
    int*    cnt  = (int*)alloc((size_t)N * 4);
    int*    gstart = (int*)alloc((size_t)(NUM_GRAPHS + 1) * 4);

    const int B = 256;
    const int gemmBlocks = (N + 63) / 64;
    const int buildBlocks = (E + N + B - 1) / B;
    const int aggBlocks = ((size_t)N * 64 + B - 1) / B;

    // ---- K1: build + gbound + layer-1 dual GEMM, co-scheduled ----
    hipMemsetAsync(cnt, 0, (size_t)N * 4, stream);
    k_build_gemm<<<gemmBlocks + buildBlocks, B, 0, stream>>>(
        src, dst, cnt, csrF, batch, gstart,
        x, W1l, W1r, H1, F, E, N, gemmBlocks);

    // ---- layers (agg fused with following GEMM; F updated in place) ----
    k_agg_gemm<<<aggBlocks, B, 0, stream>>>(H1, F, att1, b1, cnt, csrF, W2, H2, F, N);
    k_agg_gemm<<<aggBlocks, B, 0, stream>>>(H2, F, att2, b2, cnt, csrF, W3, H1, F, N);
    k_agg16<<<aggBlocks, B, 0, stream>>>(H1, F, att3, b3, cnt, csrF, F, N);

    // ---- fused pool + final linear ----
    k_pool_final<<<(NUM_GRAPHS * 64 + B - 1) / B, B, 0, stream>>>(F, gstart, Wlin, blin, (float*)d_out);
}

// Round 11
// 482.418 us; speedup vs baseline: 1.0061x; 1.0061x over previous
//
#include <hip/hip_runtime.h>
#include <hip/hip_fp16.h>
#include <math.h>

#define NEG_SLOPE 0.2f
#define NUM_GRAPHS 256

typedef float v2f __attribute__((ext_vector_type(2)));

// ---- 8-lane group float sum; result broadcast within each 8-group ----
// row_shr prefix-sums within the 16-lane DPP row give lane7=sum(0..7),
// lane15=sum(8..15); swizzle lane'=(lane&0x18)|7 broadcasts per 8-group.
__device__ __forceinline__ float hsum8_bcast(float x) {
    x += __int_as_float(__builtin_amdgcn_update_dpp(0, __float_as_int(x), 0x111, 0xF, 0xF, false)); // row_shr:1
    x += __int_as_float(__builtin_amdgcn_update_dpp(0, __float_as_int(x), 0x112, 0xF, 0xF, false)); // row_shr:2
    x += __int_as_float(__builtin_amdgcn_update_dpp(0, __float_as_int(x), 0x114, 0xF, 0xF, false)); // row_shr:4
    return __int_as_float(__builtin_amdgcn_ds_swizzle(__float_as_int(x), 0x00F8)); // and=0x18,or=7
}

// 8-feature edge score partial: att . leaky_relu(v + xr)
__device__ __forceinline__ float edge_score8(const v2f v[4], const v2f xx[4], const v2f aa[4]) {
    v2f p = {0.f, 0.f};
#pragma unroll
    for (int i = 0; i < 4; ++i) {
        v2f t = v[i] + xx[i];
        t = __builtin_elementwise_max(t, NEG_SLOPE * t);
        p = __builtin_elementwise_fma(aa[i], t, p);
    }
    return p.x + p.y;
}

#define UNPACK8(u, v)                                       \
    v2f v[4];                                               \
    {                                                       \
        float2 f0 = __half22float2(*(__half2*)&(u).x);      \
        float2 f1 = __half22float2(*(__half2*)&(u).y);      \
        float2 f2 = __half22float2(*(__half2*)&(u).z);      \
        float2 f3 = __half22float2(*(__half2*)&(u).w);      \
        v[0] = (v2f){f0.x, f0.y}; v[1] = (v2f){f1.x, f1.y}; \
        v[2] = (v2f){f2.x, f2.y}; v[3] = (v2f){f3.x, f3.y}; \
    }

#define AGG_CONSUME8(u)                                                         \
    {                                                                           \
        UNPACK8(u, vv);                                                         \
        float pp = hsum8_bcast(edge_score8(vv, xx, aa));                        \
        float ww = __expf(pp);                                                  \
        l += ww;                                                                \
        _Pragma("unroll")                                                       \
        for (int i = 0; i < 4; ++i)                                             \
            acc[i] = __builtin_elementwise_fma(vv[i], (v2f){ww, ww}, acc[i]);   \
    }

__device__ __forceinline__ void store16_f16(__half* Y16, int orow, int cbase, const float* acc) {
    __half2 h8[8];
#pragma unroll
    for (int c = 0; c < 8; ++c) h8[c] = __floats2half2_rn(acc[2*c], acc[2*c+1]);
    uint4* d16 = (uint4*)(Y16 + (size_t)orow * 64 + cbase);
    d16[0] = ((uint4*)h8)[0];
    d16[1] = ((uint4*)h8)[1];
}

__device__ __forceinline__ void store16_f32(float* Y32, int orow, int cbase, const float* acc) {
    float4* d32 = (float4*)(Y32 + (size_t)orow * 64 + cbase);
#pragma unroll
    for (int i = 0; i < 4; ++i) d32[i] = ((const float4*)acc)[i];
}

// ---------------- K1: heterogeneous mega-kernel ----------------
// blocks [0, gemmBlocks)            : layer-1 dual GEMM (VALU-bound)
// blocks [gemmBlocks, +buildBlocks) : edge scatter build (atomic-latency-bound) + gbound

__global__ void k_build_gemm(const int* __restrict__ src, const int* __restrict__ dst,
                             int* __restrict__ cnt, int* __restrict__ csrF,
                             const int* __restrict__ batch, int* __restrict__ gstart,
                             const float* __restrict__ X,
                             const float* __restrict__ Wl, const float* __restrict__ Wr,
                             __half* __restrict__ Yl16, float* __restrict__ Yr32,
                             int E, int N, int gemmBlocks) {
    __shared__ float sXT[64][65];
    if ((int)blockIdx.x < gemmBlocks) {
        int t = threadIdx.x;
        int r0 = blockIdx.x * 64;
        {
            int lr = t >> 2;
            int c0s = (t & 3) * 16;
            int row = r0 + lr;
            float4 tmp[4];
            if (row < N) {
                const float4* Xv = (const float4*)(X + (size_t)row * 64 + c0s);
#pragma unroll
                for (int i = 0; i < 4; ++i) tmp[i] = Xv[i];
            } else {
#pragma unroll
                for (int i = 0; i < 4; ++i) tmp[i] = make_float4(0.f, 0.f, 0.f, 0.f);
            }
#pragma unroll
            for (int i = 0; i < 4; ++i) {
                sXT[c0s + i*4 + 0][lr] = tmp[i].x;
                sXT[c0s + i*4 + 1][lr] = tmp[i].y;
                sXT[c0s + i*4 + 2][lr] = tmp[i].z;
                sXT[c0s + i*4 + 3][lr] = tmp[i].w;
            }
        }
        __syncthreads();
        int lane = t & 63;
        int cbase = __builtin_amdgcn_readfirstlane((t >> 6) * 16);
        int orow = r0 + lane;
        float accl[16], accr[16];
#pragma unroll
        for (int c = 0; c < 16; ++c) { accl[c] = 0.f; accr[c] = 0.f; }
        for (int k = 0; k < 64; ++k) {
            float xk = sXT[k][lane];
            const float* wl = Wl + k * 64 + cbase;
            const float* wr = Wr + k * 64 + cbase;
#pragma unroll
            for (int c = 0; c < 16; ++c) { accl[c] += xk * wl[c]; accr[c] += xk * wr[c]; }
        }
        if (orow < N) {
            store16_f16(Yl16, orow, cbase, accl);
            store16_f32(Yr32, orow, cbase, accr);
        }
    } else {
        int idx = ((int)blockIdx.x - gemmBlocks) * blockDim.x + threadIdx.x;
        if (idx < E) {
            int d = dst[idx];
            int slot = atomicAdd(&cnt[d], 1);
            if (slot < 64) csrF[((size_t)d << 6) + slot] = src[idx];
        } else if (idx < E + N) {
            int i = idx - E;
            int b = batch[i];
            if (i == 0) {
                for (int g = 0; g <= b; ++g) gstart[g] = 0;
            } else {
                int pb = batch[i - 1];
                for (int g = pb + 1; g <= b; ++g) gstart[g] = i;
            }
            if (i == N - 1) {
                for (int g = b + 1; g <= NUM_GRAPHS; ++g) gstart[g] = N;
            }
        }
    }
}

// ---------------- GEMM [N,64]@[64,64] (layers 2/3); Y32 may alias X ----------------
// In-place safe: block b reads only rows [64b,64b+64) (staged to LDS) and
// writes exactly those rows.

__global__ void k_gemm_l2(const float* X, const float* __restrict__ W,
                          __half* __restrict__ Y16, float* Y32, int N) {
    __shared__ float sXT[64][65];
    int t = threadIdx.x;
    int r0 = blockIdx.x * 64;
    {
        int lr = t >> 2;
        int c0s = (t & 3) * 16;
        int row = r0 + lr;
        float4 tmp[4];
        if (row < N) {
            const float4* Xv = (const float4*)(X + (size_t)row * 64 + c0s);
#pragma unroll
            for (int i = 0; i < 4; ++i) tmp[i] = Xv[i];
        } else {
#pragma unroll
            for (int i = 0; i < 4; ++i) tmp[i] = make_float4(0.f, 0.f, 0.f, 0.f);
        }
#pragma unroll
        for (int i = 0; i < 4; ++i) {
            sXT[c0s + i*4 + 0][lr] = tmp[i].x;
            sXT[c0s + i*4 + 1][lr] = tmp[i].y;
            sXT[c0s + i*4 + 2][lr] = tmp[i].z;
            sXT[c0s + i*4 + 3][lr] = tmp[i].w;
        }
    }
    __syncthreads();
    int lane = t & 63;
    int cbase = __builtin_amdgcn_readfirstlane((t >> 6) * 16);
    int orow = r0 + lane;
    float acc[16];
#pragma unroll
    for (int c = 0; c < 16; ++c) acc[c] = 0.f;
    for (int k = 0; k < 64; ++k) {
        float xk = sXT[k][lane];
        const float* wp = W + k * 64 + cbase;
#pragma unroll
        for (int c = 0; c < 16; ++c) acc[c] += xk * wp[c];
    }
    if (orow < N) {
        store16_f16(Y16, orow, cbase, acc);
        store16_f32(Y32, orow, cbase, acc);
    }
}

// ---------------- fused GATv2 aggregation: 8 edges/wave (8 lanes each) ----------------
// lane: slot = lane>>3 (edge index in group of 8), q = lane&7 (8 feats/lane).
// One uint4 gather instruction covers 8 rows (128B each). Software-pipelined
// (current + prefetched uint4 = 16 edges in flight). Implicit self-loop.
// out may alias xr (row wid touched only by wave wid).

__global__ void k_agg(const __half* __restrict__ xl, const float* xr,
                      const float* __restrict__ att, const float* __restrict__ bias,
                      const int* __restrict__ cnt, const int* __restrict__ csrF,
                      float* out, int N, int do_relu) {
    int wid = (blockIdx.x * blockDim.x + threadIdx.x) >> 6;
    if (wid >= N) return;
    int lane = threadIdx.x & 63;
    int q = lane & 7, slot = lane >> 3;

    // issue loop metadata + first gather as early as possible
    int deg = cnt[wid];
    deg = (deg < 64) ? deg : 64;  // csrF capacity guard
    const int* crow = csrF + ((size_t)wid << 6);
    int n8 = deg & ~7;
    uint4 u;
    if (n8 >= 8) {
        int s = crow[slot];
        u = *(const uint4*)(xl + ((size_t)s << 6) + 8 * q);
    }

    // xr/att (8 feats/lane) + self-loop compute overlap the first gather's latency
    v2f xx[4], aa[4];
    {
        float4 x0 = *(const float4*)(xr + (size_t)wid * 64 + 8 * q);
        float4 x1 = *(const float4*)(xr + (size_t)wid * 64 + 8 * q + 4);
        xx[0] = (v2f){x0.x, x0.y}; xx[1] = (v2f){x0.z, x0.w};
        xx[2] = (v2f){x1.x, x1.y}; xx[3] = (v2f){x1.z, x1.w};
        float4 a0 = *(const float4*)(att + 8 * q);
        float4 a1 = *(const float4*)(att + 8 * q + 4);
        aa[0] = (v2f){a0.x, a0.y}; aa[1] = (v2f){a0.z, a0.w};
        aa[2] = (v2f){a1.x, a1.y}; aa[3] = (v2f){a1.z, a1.w};
    }
    uint4 us = *(const uint4*)(xl + ((size_t)wid << 6) + 8 * q);
    UNPACK8(us, vs);
    float ps = hsum8_bcast(edge_score8(vs, xx, aa));
    float wsf = (slot == 0) ? __expf(ps) : 0.f;
    float l = wsf;
    v2f acc[4];
#pragma unroll
    for (int i = 0; i < 4; ++i) acc[i] = vs[i] * (v2f){wsf, wsf};

    if (n8 >= 8) {
        for (int j = 8; j < n8; j += 8) {
            int s2 = crow[j + slot];
            uint4 u2 = *(const uint4*)(xl + ((size_t)s2 << 6) + 8 * q);
            AGG_CONSUME8(u);
            u = u2;
        }
        AGG_CONSUME8(u);
    }
    if (n8 < deg) {  // masked tail: 1..7 edges in one step
        int jj = n8 + slot;
        bool valid = jj < deg;
        int s = valid ? crow[jj] : wid;
        uint4 ut = *(const uint4*)(xl + ((size_t)s << 6) + 8 * q);
        UNPACK8(ut, vt);
        float p = hsum8_bcast(edge_score8(vt, xx, aa));
        float w = valid ? __expf(p) : 0.f;
        l += w;
#pragma unroll
        for (int i = 0; i < 4; ++i)
            acc[i] = __builtin_elementwise_fma(vt[i], (v2f){w, w}, acc[i]);
    }

    // cross-slot reduce (8 slots) + write (slot 0)
#pragma unroll
    for (int o = 8; o <= 32; o <<= 1) {
        l += __shfl_xor(l, o, 64);
#pragma unroll
        for (int i = 0; i < 4; ++i) {
            acc[i].x += __shfl_xor(acc[i].x, o, 64);
            acc[i].y += __shfl_xor(acc[i].y, o, 64);
        }
    }
    if (slot == 0) {
        float rl = 1.0f / l;
        float4 b0 = *(const float4*)(bias + 8 * q);
        float4 b1 = *(const float4*)(bias + 8 * q + 4);
        float o0 = acc[0].x * rl + b0.x;
        float o1 = acc[0].y * rl + b0.y;
        float o2 = acc[1].x * rl + b0.z;
        float o3 = acc[1].y * rl + b0.w;
        float o4 = acc[2].x * rl + b1.x;
        float o5 = acc[2].y * rl + b1.y;
        float o6 = acc[3].x * rl + b1.z;
        float o7 = acc[3].y * rl + b1.w;
        if (do_relu) {
            o0 = fmaxf(o0, 0.f); o1 = fmaxf(o1, 0.f);
            o2 = fmaxf(o2, 0.f); o3 = fmaxf(o3, 0.f);
            o4 = fmaxf(o4, 0.f); o5 = fmaxf(o5, 0.f);
            o6 = fmaxf(o6, 0.f); o7 = fmaxf(o7, 0.f);
        }
        float4* op = (float4*)(out + (size_t)wid * 64 + 8 * q);
        op[0] = make_float4(o0, o1, o2, o3);
        op[1] = make_float4(o4, o5, o6, o7);
    }
}

// ---------------- fused mean pool + final linear ----------------

__global__ void k_pool_final(const float* __restrict__ h, const int* __restrict__ gstart,
                             const float* __restrict__ Wlin, const float* __restrict__ blin,
                             float* __restrict__ out) {
    int wave = (blockIdx.x * blockDim.x + threadIdx.x) >> 6;
    int lane = threadIdx.x & 63;
    if (wave >= NUM_GRAPHS) return;
    int g = wave;
    int i0 = gstart[g], i1 = gstart[g + 1];
    float s0 = 0.f, s1 = 0.f, s2 = 0.f, s3 = 0.f;
    int i = i0;
    for (; i + 4 <= i1; i += 4) {
        s0 += h[(size_t)i * 64 + lane];
        s1 += h[(size_t)(i + 1) * 64 + lane];
        s2 += h[(size_t)(i + 2) * 64 + lane];
        s3 += h[(size_t)(i + 3) * 64 + lane];
    }
    for (; i < i1; ++i) s0 += h[(size_t)i * 64 + lane];
    float s = (s0 + s1) + (s2 + s3);
    float c = (float)((i1 - i0) > 1 ? (i1 - i0) : 1);
    float pld = s / c;
    float acc = blin[lane];
    for (int k = 0; k < 64; ++k) {
        acc += __shfl(pld, k, 64) * Wlin[k * 64 + lane];
    }
    out[g * 64 + lane] = acc;
}

// ---------------- launch ----------------

extern "C" void kernel_launch(void* const* d_in, const int* in_sizes, int n_in,
                              void* d_out, int out_size, void* d_ws, size_t ws_size,
                              hipStream_t stream) {
    const float* x    = (const float*)d_in[0];
    const int*   ei   = (const int*)d_in[1];
    const int*   batch= (const int*)d_in[2];
    const float* W1l  = (const float*)d_in[3];
    const float* W1r  = (const float*)d_in[4];
    const float* att1 = (const float*)d_in[5];
    const float* b1   = (const float*)d_in[6];
    const float* W2   = (const float*)d_in[7];
    const float* att2 = (const float*)d_in[8];
    const float* b2   = (const float*)d_in[9];
    const float* W3   = (const float*)d_in[10];
    const float* att3 = (const float*)d_in[11];
    const float* b3   = (const float*)d_in[12];
    const float* Wlin = (const float*)d_in[13];
    const float* blin = (const float*)d_in[14];

    const int N = in_sizes[0] / 64;
    const int E = in_sizes[1] / 2;
    const int* src = ei;
    const int* dst = ei + E;

    char* p = (char*)d_ws;
    auto alloc = [&](size_t bytes) -> void* {
        void* r = (void*)p;
        p += (bytes + 255) & ~(size_t)255;
        return r;
    };
    float*  F    = (float*)alloc((size_t)N * 64 * 4);    // fp32 feature buffer (in-place)
    __half* H1   = (__half*)alloc((size_t)N * 64 * 2);   // fp16 gather payload (ping)
    __half* H2   = (__half*)alloc((size_t)N * 64 * 2);   // fp16 gather payload (pong)
    int*    csrF = (int*)alloc((size_t)N * 64 * 4);      // fixed-stride CSR, 64 slots/node
    int*    cnt  = (int*)alloc((size_t)N * 4);
    int*    gstart = (int*)alloc((size_t)(NUM_GRAPHS + 1) * 4);

    const int B = 256;
    const int gemmBlocks = (N + 63) / 64;
    const int buildBlocks = (E + N + B - 1) / B;
    const int aggBlocks = ((size_t)N * 64 + B - 1) / B;

    // ---- K1: build + gbound + layer-1 dual GEMM, co-scheduled ----
    hipMemsetAsync(cnt, 0, (size_t)N * 4, stream);
    k_build_gemm<<<gemmBlocks + buildBlocks, B, 0, stream>>>(
        src, dst, cnt, csrF, batch, gstart,
        x, W1l, W1r, H1, F, E, N, gemmBlocks);

    // ---- layers (agg -> gemm; F updated in place throughout) ----
    k_agg<<<aggBlocks, B, 0, stream>>>(H1, F, att1, b1, cnt, csrF, F, N, 1);
    k_gemm_l2<<<gemmBlocks, B, 0, stream>>>(F, W2, H2, F, N);
    k_agg<<<aggBlocks, B, 0, stream>>>(H2, F, att2, b2, cnt, csrF, F, N, 1);
    k_gemm_l2<<<gemmBlocks, B, 0, stream>>>(F, W3, H1, F, N);
    k_agg<<<aggBlocks, B, 0, stream>>>(H1, F, att3, b3, cnt, csrF, F, N, 0);

    // ---- fused pool + final linear ----
    k_pool_final<<<(NUM_GRAPHS * 64 + B - 1) / B, B, 0, stream>>>(F, gstart, Wlin, blin, (float*)d_out);
}